// Round 1
// baseline (125.720 us; speedup 1.0000x reference)
//
#include <hip/hip_runtime.h>

#define NQ 4096
#define NH 8
#define ND 32
#define NLV 4
#define NP 8
#define NK 30720   // 16384+8192+4096+2048

// Block = 256 threads handles 4 consecutive queries of one batch.
// Phase 1: precompute the block's 1024 (q,h,l,p) sample descriptors into LDS.
// Phase 2: thread = (qi, h, d4) accumulates a float4 of the output.
__global__ __launch_bounds__(256, 4) void spd_kernel(
    const float* __restrict__ value,   // (bs, NK, H, D)
    const float* __restrict__ loc,     // (bs, NQ, H, LV, P, 1)
    const float* __restrict__ wts,     // (bs, NQ, H, LV, P)
    float* __restrict__ out)           // (bs, NQ, H*D)
{
    const int tid = threadIdx.x;
    const int bq0 = blockIdx.x << 2;          // first flat (b*NQ + q)
    const int b   = bq0 >> 12;                // NQ = 4096

    __shared__ int   s_k1[1024];
    __shared__ int   s_k2[1024];
    __shared__ float s_w1[1024];
    __shared__ float s_w2[1024];

    // ---- Phase 1: precompute sample descriptors ----
    #pragma unroll
    for (int e = 0; e < 4; ++e) {
        const int ent = (e << 8) | tid;       // ent = qi*256 + h*32 + l*8 + p
        const size_t g = (size_t)bq0 * 256 + (size_t)ent;
        const float x_loc = loc[g];
        const float w     = wts[g];

        const int l   = (ent >> 3) & 3;
        const int L   = 16384 >> l;
        const int off = 32768 - (32768 >> l); // 0, 16384, 24576, 28672

        const float x  = x_loc * (float)L - 1.0f;
        const float xf = floorf(x);
        const float lx = x - xf;
        const float hx = 1.0f - lx;
        const int   xl = (int)xf;
        const int   xh = xl + 1;

        const bool ok1 = (xl >= 0) && (xl < L);
        const bool ok2 = (xh >= 0) && (xh < L);
        int c1 = xl < 0 ? 0 : (xl > L - 1 ? L - 1 : xl);
        int c2 = xh < 0 ? 0 : (xh > L - 1 ? L - 1 : xh);

        // transposed LDS layout: [jp=l*8+p][qi][h] -> conflict-free broadcast
        const int li = ((ent & 31) << 5) | (((ent >> 8) & 3) << 3) | ((ent >> 5) & 7);
        s_k1[li] = off + c1;
        s_k2[li] = off + c2;
        s_w1[li] = ok1 ? w * hx : 0.0f;
        s_w2[li] = ok2 ? w * lx : 0.0f;
    }
    __syncthreads();

    // ---- Phase 2: gather + accumulate ----
    const int qi = tid >> 6;         // query within block (one wave per query)
    const int h  = (tid >> 3) & 7;
    const int d4 = tid & 7;          // float4 slice of D=32

    const float4* __restrict__ v4 = (const float4*)value;
    const int    vb    = h * 8 + d4;                    // within-key float4 offset
    const size_t vbase = (size_t)b * (NK * 64) + vb;    // 64 float4 per key

    float4 acc = make_float4(0.f, 0.f, 0.f, 0.f);
    const int jb = (qi << 3) | h;

    #pragma unroll 8
    for (int j = 0; j < 32; ++j) {
        const int   li = (j << 5) | jb;
        const int   k1 = s_k1[li];
        const int   k2 = s_k2[li];
        const float w1 = s_w1[li];
        const float w2 = s_w2[li];
        const float4 a = v4[vbase + (size_t)(k1 << 6)];
        const float4 c = v4[vbase + (size_t)(k2 << 6)];
        acc.x += w1 * a.x + w2 * c.x;
        acc.y += w1 * a.y + w2 * c.y;
        acc.z += w1 * a.z + w2 * c.z;
        acc.w += w1 * a.w + w2 * c.w;
    }

    float4* __restrict__ o4 = (float4*)out;
    o4[(size_t)(bq0 + qi) * 64 + vb] = acc;
}

extern "C" void kernel_launch(void* const* d_in, const int* in_sizes, int n_in,
                              void* d_out, int out_size, void* d_ws, size_t ws_size,
                              hipStream_t stream) {
    const float* value = (const float*)d_in[0];
    const float* loc   = (const float*)d_in[1];
    const float* wts   = (const float*)d_in[2];
    float* out = (float*)d_out;

    const int bs = 4;
    const int blocks = bs * NQ / 4;   // 4096
    spd_kernel<<<blocks, 256, 0, stream>>>(value, loc, wts, out);
}

// Round 2
// 104.143 us; speedup vs baseline: 1.2072x; 1.2072x over previous
//
#include <hip/hip_runtime.h>
#include <hip/hip_fp16.h>

#define NQ 4096
#define NH 8
#define ND 32
#define NK 30720   // 16384+8192+4096+2048
#define LDSS 33    // padded LDS row stride (kills 32-way write conflicts)

// ---- Pre-pass: value fp32 -> fp16 into workspace (halves gather traffic) ----
__global__ __launch_bounds__(256) void cvt_kernel(const float* __restrict__ v,
                                                  uint4* __restrict__ o, int n8) {
    int i = blockIdx.x * blockDim.x + threadIdx.x;
    const float4* __restrict__ v4 = (const float4*)v;
    for (; i < n8; i += gridDim.x * blockDim.x) {
        const float4 f0 = v4[2 * i];
        const float4 f1 = v4[2 * i + 1];
        __half2 h0 = __floats2half2_rn(f0.x, f0.y);
        __half2 h1 = __floats2half2_rn(f0.z, f0.w);
        __half2 h2 = __floats2half2_rn(f1.x, f1.y);
        __half2 h3 = __floats2half2_rn(f1.z, f1.w);
        uint4 u;
        u.x = *reinterpret_cast<unsigned*>(&h0);
        u.y = *reinterpret_cast<unsigned*>(&h1);
        u.z = *reinterpret_cast<unsigned*>(&h2);
        u.w = *reinterpret_cast<unsigned*>(&h3);
        o[i] = u;
    }
}

// Block = 256 threads handles 4 consecutive queries of one batch.
// Phase 1: precompute the block's 1024 (q,h,l,p) sample descriptors into LDS.
// Phase 2: thread = (qi, h, d4) accumulates a float4 of the output.
template <bool FP16>
__global__ __launch_bounds__(256, 4) void spd_kernel(
    const float* __restrict__ value,   // (bs, NK, H, D) fp32
    const __half* __restrict__ vh,     // same, fp16 (workspace), if FP16
    const float* __restrict__ loc,     // (bs, NQ, H, LV, P, 1)
    const float* __restrict__ wts,     // (bs, NQ, H, LV, P)
    float* __restrict__ out)           // (bs, NQ, H*D)
{
    const int tid = threadIdx.x;
    // XCD swizzle: XCD = launched bid % 8; give each XCD one batch's chunk.
    const int vbid = ((blockIdx.x & 7) << 9) | (blockIdx.x >> 3);
    const int bq0 = vbid << 2;                // first flat (b*NQ + q)
    const int b   = bq0 >> 12;                // NQ = 4096

    __shared__ int   s_k1[32 * LDSS];
    __shared__ int   s_k2[32 * LDSS];
    __shared__ float s_w1[32 * LDSS];
    __shared__ float s_w2[32 * LDSS];

    // ---- Phase 1: precompute sample descriptors ----
    #pragma unroll
    for (int e = 0; e < 4; ++e) {
        const int ent = (e << 8) | tid;       // ent = qi*256 + h*32 + l*8 + p
        const size_t g = (size_t)bq0 * 256 + (size_t)ent;
        const float x_loc = loc[g];
        const float w     = wts[g];

        const int l   = (ent >> 3) & 3;
        const int L   = 16384 >> l;
        const int off = 32768 - (32768 >> l); // 0, 16384, 24576, 28672

        const float x  = x_loc * (float)L - 1.0f;
        const float xf = floorf(x);
        const float lx = x - xf;
        const float hx = 1.0f - lx;
        const int   xl = (int)xf;
        const int   xh = xl + 1;

        const bool ok1 = (xl >= 0) && (xl < L);
        const bool ok2 = (xh >= 0) && (xh < L);
        int c1 = xl < 0 ? 0 : (xl > L - 1 ? L - 1 : xl);
        int c2 = xh < 0 ? 0 : (xh > L - 1 ? L - 1 : xh);

        // row = l*8+p (j), col = qi*8+h ; stride 33 -> conflict-free writes+reads
        const int li = (ent & 31) * LDSS + ((((ent >> 8) & 3) << 3) | ((ent >> 5) & 7));
        s_k1[li] = off + c1;
        s_k2[li] = off + c2;
        s_w1[li] = ok1 ? w * hx : 0.0f;
        s_w2[li] = ok2 ? w * lx : 0.0f;
    }
    __syncthreads();

    // ---- Phase 2: gather + accumulate ----
    const int qi = tid >> 6;         // query within block (one wave per query)
    const int h  = (tid >> 3) & 7;
    const int d4 = tid & 7;          // float4 slice of D=32
    const int cb = (qi << 3) | h;

    float4 acc0 = make_float4(0.f, 0.f, 0.f, 0.f);
    float4 acc1 = make_float4(0.f, 0.f, 0.f, 0.f);

    if (FP16) {
        const uint2* __restrict__ v2 = (const uint2*)vh;   // 4 halves per uint2
        const size_t vbase = (size_t)b * (NK * 64) + (h << 3) + d4;
        #pragma unroll 16
        for (int j = 0; j < 32; ++j) {
            const int   li = j * LDSS + cb;
            const int   k1 = s_k1[li];
            const int   k2 = s_k2[li];
            const float w1 = s_w1[li];
            const float w2 = s_w2[li];
            const uint2 r1 = v2[vbase + (size_t)k1 * 64];
            const uint2 r2 = v2[vbase + (size_t)k2 * 64];
            const float2 a0 = __half22float2(*(const __half2*)&r1.x);
            const float2 a1 = __half22float2(*(const __half2*)&r1.y);
            const float2 c0 = __half22float2(*(const __half2*)&r2.x);
            const float2 c1 = __half22float2(*(const __half2*)&r2.y);
            float4& acc = (j & 1) ? acc1 : acc0;
            acc.x += w1 * a0.x + w2 * c0.x;
            acc.y += w1 * a0.y + w2 * c0.y;
            acc.z += w1 * a1.x + w2 * c1.x;
            acc.w += w1 * a1.y + w2 * c1.y;
        }
    } else {
        const float4* __restrict__ v4 = (const float4*)value;
        const size_t vbase = (size_t)b * (NK * 64) + (h << 3) + d4;
        #pragma unroll 16
        for (int j = 0; j < 32; ++j) {
            const int   li = j * LDSS + cb;
            const int   k1 = s_k1[li];
            const int   k2 = s_k2[li];
            const float w1 = s_w1[li];
            const float w2 = s_w2[li];
            const float4 a = v4[vbase + (size_t)(k1 << 6)];
            const float4 c = v4[vbase + (size_t)(k2 << 6)];
            float4& acc = (j & 1) ? acc1 : acc0;
            acc.x += w1 * a.x + w2 * c.x;
            acc.y += w1 * a.y + w2 * c.y;
            acc.z += w1 * a.z + w2 * c.z;
            acc.w += w1 * a.w + w2 * c.w;
        }
    }

    acc0.x += acc1.x; acc0.y += acc1.y; acc0.z += acc1.z; acc0.w += acc1.w;
    float4* __restrict__ o4 = (float4*)out;
    o4[(size_t)(bq0 + qi) * 64 + ((h << 3) | d4)] = acc0;
}

extern "C" void kernel_launch(void* const* d_in, const int* in_sizes, int n_in,
                              void* d_out, int out_size, void* d_ws, size_t ws_size,
                              hipStream_t stream) {
    const float* value = (const float*)d_in[0];
    const float* loc   = (const float*)d_in[1];
    const float* wts   = (const float*)d_in[2];
    float* out = (float*)d_out;

    const int bs = 4;
    const int blocks = bs * NQ / 4;   // 4096
    const size_t need = (size_t)bs * NK * NH * ND * sizeof(__half);  // ~63 MB

    if (ws_size >= need) {
        const int n8 = bs * NK * NH * ND / 8;  // 8 floats per thread-iter
        cvt_kernel<<<2048, 256, 0, stream>>>(value, (uint4*)d_ws, n8);
        spd_kernel<true><<<blocks, 256, 0, stream>>>(value, (const __half*)d_ws,
                                                     loc, wts, out);
    } else {
        spd_kernel<false><<<blocks, 256, 0, stream>>>(value, nullptr,
                                                      loc, wts, out);
    }
}